// Round 15
// baseline (130.518 us; speedup 1.0000x reference)
//
#include <hip/hip_runtime.h>
#include <math.h>

#define NUM_FREQS   64
#define NUM_BINS    128
#define NUM_QUERIES 32768
#define HEAD_DIM    128
#define EPS         1e-8f
#define NQB         16   // queries per block (4 waves x 4 j each)

// ---------------------------------------------------------------------------
// Fused prep: blocks [0,128) normalize Q -> Qri {qr,qi} + Qm planes;
// blocks [128,160) pack probe constants for the expanded-distance form:
//   probeA[f*128+b] = { -2*Pr, -2*Pi, Pr^2+Pi^2, -softplus(w) }
//   probeM[f*128+b] = mw
// (eps is carried inside qm^2 = qr^2+qi^2+eps, so C'' needs no eps.)
// ---------------------------------------------------------------------------
__global__ void prep_fused(const float* __restrict__ Q,
                           const float* __restrict__ rp,
                           const float* __restrict__ wraw,
                           const float* __restrict__ mw,
                           float2* __restrict__ Qri,
                           float*  __restrict__ Qm,
                           float4* __restrict__ probeA,
                           float*  __restrict__ probeM) {
    const int bid = blockIdx.x;
    const int tid = threadIdx.x;
    if (bid < 128) {
        int q = bid * 256 + tid;
        const float4* Qrow = reinterpret_cast<const float4*>(Q + (size_t)q * HEAD_DIM);
        float4 buf[32];
        float s = 0.0f;
        #pragma unroll
        for (int i = 0; i < 32; i++) {
            float4 v = Qrow[i];
            buf[i] = v;
            s = fmaf(v.x, v.x, fmaf(v.y, v.y, fmaf(v.z, v.z, fmaf(v.w, v.w, s))));
        }
        float inv = 1.0f / (__builtin_amdgcn_sqrtf(s) + EPS);
        #pragma unroll
        for (int i = 0; i < 16; i++) {
            float4 r  = buf[i];
            float4 im = buf[16 + i];
            float rr[4] = { r.x,  r.y,  r.z,  r.w  };
            float ii[4] = { im.x, im.y, im.z, im.w };
            #pragma unroll
            for (int k = 0; k < 4; k++) {
                float qr = rr[k] * inv;
                float qi = ii[k] * inv;
                float qm = __builtin_amdgcn_sqrtf(fmaf(qr, qr, fmaf(qi, qi, EPS)));
                int f = 4 * i + k;
                Qri[(size_t)f * NUM_QUERIES + q] = make_float2(qr, qi);  // coalesced
                Qm [(size_t)f * NUM_QUERIES + q] = qm;
            }
        }
    } else {
        int idx = (bid - 128) * 256 + tid;       // idx = f*128 + b
        if (idx >= NUM_FREQS * NUM_BINS) return;
        int f = idx >> 7;
        int b = idx & 127;
        float pr = rp[b * HEAD_DIM + f];
        float pi = rp[b * HEAD_DIM + NUM_FREQS + f];
        float w  = wraw[b * NUM_FREQS + f];
        float sp = fmaxf(w, 0.0f) + log1pf(expf(-fabsf(w)));   // stable softplus
        probeA[idx] = make_float4(-2.0f * pr, -2.0f * pi,
                                  fmaf(pr, pr, pi * pi), -sp);
        probeM[idx] = mw[b * NUM_FREQS + f];
    }
}

// ---------------------------------------------------------------------------
// Main: block = 256 threads (4 waves); block owns 16 queries; wave w owns
// j in [4w, 4w+4); lane covers bins (lane, lane+64) -> 8 outputs per lane.
// Expanded distance: s = C'' + qm^2 - 2Pr*qr - 2Pi*qi (5 fma + 1 sqrt per
// output incl. magnitude term). Grid = 2048 blocks = 8 blocks/CU (32 w/CU).
// DEPTH-1 PIPELINE ON BOTH PIPES: LDS shadows (r01n/r23n/qm4n) and VMEM
// shadows (P0n/P1n/w0n/w1n) for f+1 are issued before a sched_barrier(0);
// compute of f follows -> lgkm/vm waits land after ~230 cy of compute.
// Guard row (+1) keeps the f=63 LDS prefetch in-bounds.
// ---------------------------------------------------------------------------
__global__ __launch_bounds__(256, 8) void main_kernel(
        const float4* __restrict__ probeA,
        const float*  __restrict__ probeM,
        const float2* __restrict__ Qri,
        const float*  __restrict__ Qm,
        const float*  __restrict__ bias,
        float*        __restrict__ out) {
    __shared__ float2 sri[NUM_FREQS + 1][NQB];   // 8.1 KB, +1 guard row
    __shared__ float  sqm[NUM_FREQS + 1][NQB];   // 4.1 KB, +1 guard row

    const int tid   = threadIdx.x;
    const int qbase = blockIdx.x * NQB;

    // Stage q-panel: 512 + 256 float4 stores, 3 per thread, coalesced.
    #pragma unroll
    for (int i = 0; i < 3; i++) {
        int idx = i * 256 + tid;
        if (idx < 512) {                       // sri: f = idx>>3, chunk = idx&7
            int f = idx >> 3, c = idx & 7;
            reinterpret_cast<float4*>(&sri[f][0])[c] =
                reinterpret_cast<const float4*>(Qri + (size_t)f * NUM_QUERIES + qbase)[c];
        } else {                               // sqm
            int t2 = idx - 512;
            int f = t2 >> 2, c = t2 & 3;
            reinterpret_cast<float4*>(&sqm[f][0])[c] =
                reinterpret_cast<const float4*>(Qm + (size_t)f * NUM_QUERIES + qbase)[c];
        }
    }
    __syncthreads();

    const int lane = tid & 63;
    const int wave = tid >> 6;
    const int jb   = wave * 4;               // this wave's j-chunk base

    float b0 = bias[lane];
    float b1 = bias[64 + lane];

    float acc0[4], acc1[4];
    #pragma unroll
    for (int p = 0; p < 4; p++) { acc0[p] = 0.0f; acc1[p] = 0.0f; }

    const float4* pA = probeA + lane;        // advances by 128 per f
    const float*  pM = probeM + lane;

    // Prologue: f = 0 into the live registers (both pipes).
    float4 P0  = pA[0];
    float4 P1  = pA[64];
    float  w0  = pM[0];
    float  w1  = pM[64];
    float4 r01 = *reinterpret_cast<const float4*>(&sri[0][jb]);
    float4 r23 = *reinterpret_cast<const float4*>(&sri[0][jb + 2]);
    float4 qm4 = *reinterpret_cast<const float4*>(&sqm[0][jb]);

    #pragma unroll 4
    for (int f = 0; f < NUM_FREQS; f++) {
        // ---- issue phase: LDS + VMEM for f+1 into shadow registers ----
        float4 r01n = *reinterpret_cast<const float4*>(&sri[f + 1][jb]);
        float4 r23n = *reinterpret_cast<const float4*>(&sri[f + 1][jb + 2]);
        float4 qm4n = *reinterpret_cast<const float4*>(&sqm[f + 1][jb]);
        pA += NUM_BINS; pM += NUM_BINS;
        float4 P0n = pA[0];                  // f=63: lands in probeM, unused
        float4 P1n = pA[64];
        float  w0n = pM[0];
        float  w1n = pM[64];
        __builtin_amdgcn_sched_barrier(0);   // keep issue phase above compute

        // ---- compute phase (uses current registers) ----
        const float qrv[4] = { r01.x, r01.z, r23.x, r23.z };
        const float qiv[4] = { r01.y, r01.w, r23.y, r23.w };
        const float qmv[4] = { qm4.x, qm4.y, qm4.z, qm4.w };

        #pragma unroll
        for (int p = 0; p < 4; p++) {
            float qr = qrv[p], qi = qiv[p], qm = qmv[p];
            {   // bin = lane
                float a = fmaf(qm, qm, P0.z);
                a = fmaf(P0.x, qr, a);
                a = fmaf(P0.y, qi, a);
                float d = __builtin_amdgcn_sqrtf(a);
                acc0[p] = fmaf(d, P0.w, fmaf(qm, w0, acc0[p]));
            }
            {   // bin = lane + 64
                float a = fmaf(qm, qm, P1.z);
                a = fmaf(P1.x, qr, a);
                a = fmaf(P1.y, qi, a);
                float d = __builtin_amdgcn_sqrtf(a);
                acc1[p] = fmaf(d, P1.w, fmaf(qm, w1, acc1[p]));
            }
        }

        // ---- rotate shadows -> live ----
        r01 = r01n; r23 = r23n; qm4 = qm4n;
        P0 = P0n; P1 = P1n; w0 = w0n; w1 = w1n;
    }

    #pragma unroll
    for (int p = 0; p < 4; p++) {
        size_t row = (size_t)(qbase + jb + p) * NUM_BINS;
        out[row + lane]      = acc0[p] + b0;     // coalesced
        out[row + 64 + lane] = acc1[p] + b1;     // coalesced
    }
}

// ---------------------------------------------------------------------------
// Fallback (only if ws_size is too small): fully self-contained, slower.
// ---------------------------------------------------------------------------
__global__ void fallback_kernel(const float* __restrict__ Q,
                                const float* __restrict__ rp,
                                const float* __restrict__ wraw,
                                const float* __restrict__ mw,
                                const float* __restrict__ bias,
                                float* __restrict__ out) {
    __shared__ float qn[HEAD_DIM];
    __shared__ float qmag[NUM_FREQS];
    __shared__ float red[NUM_BINS];
    const int t = threadIdx.x;
    const int q = blockIdx.x;

    float v = Q[(size_t)q * HEAD_DIM + t];
    red[t] = v * v;
    __syncthreads();
    for (int s = 64; s > 0; s >>= 1) {
        if (t < s) red[t] += red[t + s];
        __syncthreads();
    }
    float inv = 1.0f / (__builtin_amdgcn_sqrtf(red[0]) + EPS);
    qn[t] = v * inv;
    __syncthreads();
    if (t < NUM_FREQS) {
        float a = qn[t], c = qn[t + NUM_FREQS];
        qmag[t] = __builtin_amdgcn_sqrtf(fmaf(a, a, fmaf(c, c, EPS)));
    }
    __syncthreads();

    const int b = t;
    float acc = 0.0f;
    for (int f = 0; f < NUM_FREQS; f++) {
        float pr = rp[(size_t)b * HEAD_DIM + f];
        float pi = rp[(size_t)b * HEAD_DIM + NUM_FREQS + f];
        float w  = wraw[(size_t)b * NUM_FREQS + f];
        float ew = -(fmaxf(w, 0.0f) + log1pf(expf(-fabsf(w))));
        float er = pr - qn[f];
        float ei = pi - qn[f + NUM_FREQS];
        float d  = __builtin_amdgcn_sqrtf(fmaf(er, er, fmaf(ei, ei, EPS)));
        acc = fmaf(d, ew, fmaf(qmag[f], mw[(size_t)b * NUM_FREQS + f], acc));
    }
    out[(size_t)q * NUM_BINS + b] = acc + bias[b];
}

// ---------------------------------------------------------------------------
extern "C" void kernel_launch(void* const* d_in, const int* in_sizes, int n_in,
                              void* d_out, int out_size, void* d_ws, size_t ws_size,
                              hipStream_t stream) {
    const float* Q    = (const float*)d_in[0];
    const float* rp   = (const float*)d_in[1];
    const float* wraw = (const float*)d_in[2];
    const float* mw   = (const float*)d_in[3];
    const float* bias = (const float*)d_in[4];
    float* out = (float*)d_out;

    const size_t pABytes  = (size_t)NUM_FREQS * NUM_BINS * sizeof(float4);    // 128 KiB
    const size_t pMBytes  = (size_t)NUM_FREQS * NUM_BINS * sizeof(float);     //  32 KiB
    const size_t qriBytes = (size_t)NUM_FREQS * NUM_QUERIES * sizeof(float2); //  16 MiB
    const size_t qmBytes  = (size_t)NUM_FREQS * NUM_QUERIES * sizeof(float);  //   8 MiB
    const size_t need     = pABytes + pMBytes + qriBytes + qmBytes;           // ~24.2 MiB

    if (ws_size >= need) {
        float4* probeA = (float4*)d_ws;
        float*  probeM = (float*)((char*)d_ws + pABytes);
        float2* Qri    = (float2*)((char*)d_ws + pABytes + pMBytes);
        float*  Qm     = (float*)((char*)d_ws + pABytes + pMBytes + qriBytes);

        hipLaunchKernelGGL(prep_fused, dim3(128 + 32), dim3(256), 0, stream,
                           Q, rp, wraw, mw, Qri, Qm, probeA, probeM);
        hipLaunchKernelGGL(main_kernel, dim3(NUM_QUERIES / NQB), dim3(256), 0,
                           stream, probeA, probeM, Qri, Qm, bias, out);
    } else {
        hipLaunchKernelGGL(fallback_kernel, dim3(NUM_QUERIES), dim3(NUM_BINS), 0,
                           stream, Q, rp, wraw, mw, bias, out);
    }
}

// Round 16
// 74.200 us; speedup vs baseline: 1.7590x; 1.7590x over previous
//
#include <hip/hip_runtime.h>
#include <math.h>

#define NUM_FREQS   64
#define NUM_BINS    128
#define NUM_QUERIES 32768
#define HEAD_DIM    128
#define EPS         1e-8f
#define NQB         16   // queries per block (4 waves x 4 j each)

// ---------------------------------------------------------------------------
// Fused prep: blocks [0,128) normalize Q -> Qri {qr,qi} + Qm planes;
// blocks [128,160) pack probe constants for the expanded-distance form:
//   probeA[f*128+b] = { -2*Pr, -2*Pi, Pr^2+Pi^2, -softplus(w) }
//   probeM[f*128+b] = mw
// (eps is carried inside qm^2 = qr^2+qi^2+eps, so C'' needs no eps.)
// ---------------------------------------------------------------------------
__global__ void prep_fused(const float* __restrict__ Q,
                           const float* __restrict__ rp,
                           const float* __restrict__ wraw,
                           const float* __restrict__ mw,
                           float2* __restrict__ Qri,
                           float*  __restrict__ Qm,
                           float4* __restrict__ probeA,
                           float*  __restrict__ probeM) {
    const int bid = blockIdx.x;
    const int tid = threadIdx.x;
    if (bid < 128) {
        int q = bid * 256 + tid;
        const float4* Qrow = reinterpret_cast<const float4*>(Q + (size_t)q * HEAD_DIM);
        float4 buf[32];
        float s = 0.0f;
        #pragma unroll
        for (int i = 0; i < 32; i++) {
            float4 v = Qrow[i];
            buf[i] = v;
            s = fmaf(v.x, v.x, fmaf(v.y, v.y, fmaf(v.z, v.z, fmaf(v.w, v.w, s))));
        }
        float inv = 1.0f / (__builtin_amdgcn_sqrtf(s) + EPS);
        #pragma unroll
        for (int i = 0; i < 16; i++) {
            float4 r  = buf[i];
            float4 im = buf[16 + i];
            float rr[4] = { r.x,  r.y,  r.z,  r.w  };
            float ii[4] = { im.x, im.y, im.z, im.w };
            #pragma unroll
            for (int k = 0; k < 4; k++) {
                float qr = rr[k] * inv;
                float qi = ii[k] * inv;
                float qm = __builtin_amdgcn_sqrtf(fmaf(qr, qr, fmaf(qi, qi, EPS)));
                int f = 4 * i + k;
                Qri[(size_t)f * NUM_QUERIES + q] = make_float2(qr, qi);  // coalesced
                Qm [(size_t)f * NUM_QUERIES + q] = qm;
            }
        }
    } else {
        int idx = (bid - 128) * 256 + tid;       // idx = f*128 + b
        if (idx >= NUM_FREQS * NUM_BINS) return;
        int f = idx >> 7;
        int b = idx & 127;
        float pr = rp[b * HEAD_DIM + f];
        float pi = rp[b * HEAD_DIM + NUM_FREQS + f];
        float w  = wraw[b * NUM_FREQS + f];
        float sp = fmaxf(w, 0.0f) + log1pf(expf(-fabsf(w)));   // stable softplus
        probeA[idx] = make_float4(-2.0f * pr, -2.0f * pi,
                                  fmaf(pr, pr, pi * pi), -sp);
        probeM[idx] = mw[b * NUM_FREQS + f];
    }
}

// ---------------------------------------------------------------------------
// Main: block = 256 threads (4 waves); block owns 16 queries; wave w owns
// j in [4w, 4w+4); lane covers bins (lane, lane+64) -> 8 outputs per lane.
// Expanded distance: s = C'' + qm^2 - 2Pr*qr - 2Pi*qi (5 fma + 1 sqrt per
// output incl. magnitude term). Grid = 2048 blocks; ~12.8 KB LDS.
// DEPTH-1 PIPELINE ON BOTH PIPES: LDS shadows (r01n/r23n/qm4n) and VMEM
// shadows (P0n/P1n/w0n/w1n) for f+1 issued before a sched_barrier(0);
// compute of f follows -> lgkm/vm waits land after ~230 cy of compute.
// __launch_bounds__(256,4): 128-VGPR allowance so the ~54-VGPR shadow set
// stays in registers (R15's (256,8)=64 cap made hipcc spill it to scratch);
// if actual VGPR <= 64 the runtime occupancy is still 8 blocks/CU.
// ---------------------------------------------------------------------------
__global__ __launch_bounds__(256, 4) void main_kernel(
        const float4* __restrict__ probeA,
        const float*  __restrict__ probeM,
        const float2* __restrict__ Qri,
        const float*  __restrict__ Qm,
        const float*  __restrict__ bias,
        float*        __restrict__ out) {
    __shared__ float2 sri[NUM_FREQS + 1][NQB];   // 8.1 KB, +1 guard row
    __shared__ float  sqm[NUM_FREQS + 1][NQB];   // 4.1 KB, +1 guard row

    const int tid   = threadIdx.x;
    const int qbase = blockIdx.x * NQB;

    // Stage q-panel: 512 + 256 float4 stores, 3 per thread, coalesced.
    #pragma unroll
    for (int i = 0; i < 3; i++) {
        int idx = i * 256 + tid;
        if (idx < 512) {                       // sri: f = idx>>3, chunk = idx&7
            int f = idx >> 3, c = idx & 7;
            reinterpret_cast<float4*>(&sri[f][0])[c] =
                reinterpret_cast<const float4*>(Qri + (size_t)f * NUM_QUERIES + qbase)[c];
        } else {                               // sqm
            int t2 = idx - 512;
            int f = t2 >> 2, c = t2 & 3;
            reinterpret_cast<float4*>(&sqm[f][0])[c] =
                reinterpret_cast<const float4*>(Qm + (size_t)f * NUM_QUERIES + qbase)[c];
        }
    }
    __syncthreads();

    const int lane = tid & 63;
    const int wave = tid >> 6;
    const int jb   = wave * 4;               // this wave's j-chunk base

    float b0 = bias[lane];
    float b1 = bias[64 + lane];

    float acc0[4], acc1[4];
    #pragma unroll
    for (int p = 0; p < 4; p++) { acc0[p] = 0.0f; acc1[p] = 0.0f; }

    const float4* pA = probeA + lane;        // advances by 128 per f
    const float*  pM = probeM + lane;

    // Prologue: f = 0 into the live registers (both pipes).
    float4 P0  = pA[0];
    float4 P1  = pA[64];
    float  w0  = pM[0];
    float  w1  = pM[64];
    float4 r01 = *reinterpret_cast<const float4*>(&sri[0][jb]);
    float4 r23 = *reinterpret_cast<const float4*>(&sri[0][jb + 2]);
    float4 qm4 = *reinterpret_cast<const float4*>(&sqm[0][jb]);

    #pragma unroll 4
    for (int f = 0; f < NUM_FREQS; f++) {
        // ---- issue phase: LDS + VMEM for f+1 into shadow registers ----
        float4 r01n = *reinterpret_cast<const float4*>(&sri[f + 1][jb]);
        float4 r23n = *reinterpret_cast<const float4*>(&sri[f + 1][jb + 2]);
        float4 qm4n = *reinterpret_cast<const float4*>(&sqm[f + 1][jb]);
        pA += NUM_BINS; pM += NUM_BINS;
        float4 P0n = pA[0];                  // f=63: lands in probeM, unused
        float4 P1n = pA[64];
        float  w0n = pM[0];
        float  w1n = pM[64];
        __builtin_amdgcn_sched_barrier(0);   // keep issue phase above compute

        // ---- compute phase (uses current registers) ----
        const float qrv[4] = { r01.x, r01.z, r23.x, r23.z };
        const float qiv[4] = { r01.y, r01.w, r23.y, r23.w };
        const float qmv[4] = { qm4.x, qm4.y, qm4.z, qm4.w };

        #pragma unroll
        for (int p = 0; p < 4; p++) {
            float qr = qrv[p], qi = qiv[p], qm = qmv[p];
            {   // bin = lane
                float a = fmaf(qm, qm, P0.z);
                a = fmaf(P0.x, qr, a);
                a = fmaf(P0.y, qi, a);
                float d = __builtin_amdgcn_sqrtf(a);
                acc0[p] = fmaf(d, P0.w, fmaf(qm, w0, acc0[p]));
            }
            {   // bin = lane + 64
                float a = fmaf(qm, qm, P1.z);
                a = fmaf(P1.x, qr, a);
                a = fmaf(P1.y, qi, a);
                float d = __builtin_amdgcn_sqrtf(a);
                acc1[p] = fmaf(d, P1.w, fmaf(qm, w1, acc1[p]));
            }
        }

        // ---- rotate shadows -> live ----
        r01 = r01n; r23 = r23n; qm4 = qm4n;
        P0 = P0n; P1 = P1n; w0 = w0n; w1 = w1n;
    }

    #pragma unroll
    for (int p = 0; p < 4; p++) {
        size_t row = (size_t)(qbase + jb + p) * NUM_BINS;
        out[row + lane]      = acc0[p] + b0;     // coalesced
        out[row + 64 + lane] = acc1[p] + b1;     // coalesced
    }
}

// ---------------------------------------------------------------------------
// Fallback (only if ws_size is too small): fully self-contained, slower.
// ---------------------------------------------------------------------------
__global__ void fallback_kernel(const float* __restrict__ Q,
                                const float* __restrict__ rp,
                                const float* __restrict__ wraw,
                                const float* __restrict__ mw,
                                const float* __restrict__ bias,
                                float* __restrict__ out) {
    __shared__ float qn[HEAD_DIM];
    __shared__ float qmag[NUM_FREQS];
    __shared__ float red[NUM_BINS];
    const int t = threadIdx.x;
    const int q = blockIdx.x;

    float v = Q[(size_t)q * HEAD_DIM + t];
    red[t] = v * v;
    __syncthreads();
    for (int s = 64; s > 0; s >>= 1) {
        if (t < s) red[t] += red[t + s];
        __syncthreads();
    }
    float inv = 1.0f / (__builtin_amdgcn_sqrtf(red[0]) + EPS);
    qn[t] = v * inv;
    __syncthreads();
    if (t < NUM_FREQS) {
        float a = qn[t], c = qn[t + NUM_FREQS];
        qmag[t] = __builtin_amdgcn_sqrtf(fmaf(a, a, fmaf(c, c, EPS)));
    }
    __syncthreads();

    const int b = t;
    float acc = 0.0f;
    for (int f = 0; f < NUM_FREQS; f++) {
        float pr = rp[(size_t)b * HEAD_DIM + f];
        float pi = rp[(size_t)b * HEAD_DIM + NUM_FREQS + f];
        float w  = wraw[(size_t)b * NUM_FREQS + f];
        float ew = -(fmaxf(w, 0.0f) + log1pf(expf(-fabsf(w))));
        float er = pr - qn[f];
        float ei = pi - qn[f + NUM_FREQS];
        float d  = __builtin_amdgcn_sqrtf(fmaf(er, er, fmaf(ei, ei, EPS)));
        acc = fmaf(d, ew, fmaf(qmag[f], mw[(size_t)b * NUM_FREQS + f], acc));
    }
    out[(size_t)q * NUM_BINS + b] = acc + bias[b];
}

// ---------------------------------------------------------------------------
extern "C" void kernel_launch(void* const* d_in, const int* in_sizes, int n_in,
                              void* d_out, int out_size, void* d_ws, size_t ws_size,
                              hipStream_t stream) {
    const float* Q    = (const float*)d_in[0];
    const float* rp   = (const float*)d_in[1];
    const float* wraw = (const float*)d_in[2];
    const float* mw   = (const float*)d_in[3];
    const float* bias = (const float*)d_in[4];
    float* out = (float*)d_out;

    const size_t pABytes  = (size_t)NUM_FREQS * NUM_BINS * sizeof(float4);    // 128 KiB
    const size_t pMBytes  = (size_t)NUM_FREQS * NUM_BINS * sizeof(float);     //  32 KiB
    const size_t qriBytes = (size_t)NUM_FREQS * NUM_QUERIES * sizeof(float2); //  16 MiB
    const size_t qmBytes  = (size_t)NUM_FREQS * NUM_QUERIES * sizeof(float);  //   8 MiB
    const size_t need     = pABytes + pMBytes + qriBytes + qmBytes;           // ~24.2 MiB

    if (ws_size >= need) {
        float4* probeA = (float4*)d_ws;
        float*  probeM = (float*)((char*)d_ws + pABytes);
        float2* Qri    = (float2*)((char*)d_ws + pABytes + pMBytes);
        float*  Qm     = (float*)((char*)d_ws + pABytes + pMBytes + qriBytes);

        hipLaunchKernelGGL(prep_fused, dim3(128 + 32), dim3(256), 0, stream,
                           Q, rp, wraw, mw, Qri, Qm, probeA, probeM);
        hipLaunchKernelGGL(main_kernel, dim3(NUM_QUERIES / NQB), dim3(256), 0,
                           stream, probeA, probeM, Qri, Qm, bias, out);
    } else {
        hipLaunchKernelGGL(fallback_kernel, dim3(NUM_QUERIES), dim3(NUM_BINS), 0,
                           stream, Q, rp, wraw, mw, bias, out);
    }
}

// Round 17
// 67.092 us; speedup vs baseline: 1.9453x; 1.1059x over previous
//
#include <hip/hip_runtime.h>
#include <math.h>

#define NUM_FREQS   64
#define NUM_BINS    128
#define NUM_QUERIES 32768
#define HEAD_DIM    128
#define EPS         1e-8f
#define NQB         16   // queries per block (4 waves x 4 j each)

// ---------------------------------------------------------------------------
// Prep (probe only now): probeA[f*128+b] = { -2Pr, -2Pi, Pr^2+Pi^2, -softplus }
//                        probeM[f*128+b] = mw
// Grid = 32 blocks x 256 threads = 8192 entries.
// ---------------------------------------------------------------------------
__global__ void prep_probe(const float* __restrict__ rp,
                           const float* __restrict__ wraw,
                           const float* __restrict__ mw,
                           float4* __restrict__ probeA,
                           float*  __restrict__ probeM) {
    int idx = blockIdx.x * 256 + threadIdx.x;    // idx = f*128 + b
    if (idx >= NUM_FREQS * NUM_BINS) return;
    int f = idx >> 7;
    int b = idx & 127;
    float pr = rp[b * HEAD_DIM + f];
    float pi = rp[b * HEAD_DIM + NUM_FREQS + f];
    float w  = wraw[b * NUM_FREQS + f];
    float sp = fmaxf(w, 0.0f) + log1pf(expf(-fabsf(w)));   // stable softplus
    probeA[idx] = make_float4(-2.0f * pr, -2.0f * pi,
                              fmaf(pr, pr, pi * pi), -sp);
    probeM[idx] = mw[b * NUM_FREQS + f];
}

// ---------------------------------------------------------------------------
// Main: block = 256 threads (4 waves); block owns 16 queries; wave w owns
// j in [4w, 4w+4); lane covers bins (lane, lane+64) -> 8 outputs per lane.
// IN-BLOCK Q-PREP (replaces the old prep_q kernel + 24 MB plane round-trip):
// read the block's 16 Q rows (8 KB coalesced), row-norm via 32-lane shfl_xor
// reduce, scatter {qr,qi} into sri, then derive sqm from sri.
// Main loop identical to R16: expanded distance, depth-1 shadow pipeline on
// both pipes, sched_barrier(0) between issue and compute phases.
// ---------------------------------------------------------------------------
__global__ __launch_bounds__(256, 4) void main_kernel(
        const float4* __restrict__ probeA,
        const float*  __restrict__ probeM,
        const float*  __restrict__ Q,
        const float*  __restrict__ bias,
        float*        __restrict__ out) {
    __shared__ float2 sri[NUM_FREQS + 1][NQB];   // 8.1 KB, +1 guard row
    __shared__ float  sqm[NUM_FREQS + 1][NQB];   // 4.1 KB, +1 guard row

    const int tid   = threadIdx.x;
    const int qbase = blockIdx.x * NQB;

    // ---- in-block q-prep ----
    // 16 rows x 32 float4-chunks; thread t holds chunk (t&31) of rows
    // r1 = t>>5 (0..7) and r2 = r1+8. Rows are contiguous 32-lane groups.
    {
        const float4* Qb = reinterpret_cast<const float4*>(Q + (size_t)qbase * HEAD_DIM);
        float4 v1 = Qb[tid];
        float4 v2 = Qb[tid + 256];
        const int c  = tid & 31;
        const int r1 = tid >> 5;
        const int r2 = r1 + 8;

        float s1 = fmaf(v1.x, v1.x, fmaf(v1.y, v1.y, fmaf(v1.z, v1.z, v1.w * v1.w)));
        float s2 = fmaf(v2.x, v2.x, fmaf(v2.y, v2.y, fmaf(v2.z, v2.z, v2.w * v2.w)));
        #pragma unroll
        for (int off = 1; off < 32; off <<= 1) {   // reduce within 32-lane group
            s1 += __shfl_xor(s1, off);
            s2 += __shfl_xor(s2, off);
        }
        float inv1 = 1.0f / (__builtin_amdgcn_sqrtf(s1) + EPS);
        float inv2 = 1.0f / (__builtin_amdgcn_sqrtf(s2) + EPS);

        const float a1[4] = { v1.x, v1.y, v1.z, v1.w };
        const float a2[4] = { v2.x, v2.y, v2.z, v2.w };
        #pragma unroll
        for (int k = 0; k < 4; k++) {
            int d = 4 * c + k;
            float x1 = a1[k] * inv1;
            float x2 = a2[k] * inv2;
            if (d < NUM_FREQS) {
                sri[d][r1].x = x1;
                sri[d][r2].x = x2;
            } else {
                sri[d - NUM_FREQS][r1].y = x1;
                sri[d - NUM_FREQS][r2].y = x2;
            }
        }
    }
    __syncthreads();
    // qm plane from sri: 1024 entries, 4 per thread.
    #pragma unroll
    for (int i = 0; i < 4; i++) {
        int e = i * 256 + tid;
        int f = e >> 4, j = e & 15;
        float2 ri = sri[f][j];
        sqm[f][j] = __builtin_amdgcn_sqrtf(fmaf(ri.x, ri.x, fmaf(ri.y, ri.y, EPS)));
    }
    __syncthreads();

    const int lane = tid & 63;
    const int wave = tid >> 6;
    const int jb   = wave * 4;               // this wave's j-chunk base

    float b0 = bias[lane];
    float b1 = bias[64 + lane];

    float acc0[4], acc1[4];
    #pragma unroll
    for (int p = 0; p < 4; p++) { acc0[p] = 0.0f; acc1[p] = 0.0f; }

    const float4* pA = probeA + lane;        // advances by 128 per f
    const float*  pM = probeM + lane;

    // Prologue: f = 0 into the live registers (both pipes).
    float4 P0  = pA[0];
    float4 P1  = pA[64];
    float  w0  = pM[0];
    float  w1  = pM[64];
    float4 r01 = *reinterpret_cast<const float4*>(&sri[0][jb]);
    float4 r23 = *reinterpret_cast<const float4*>(&sri[0][jb + 2]);
    float4 qm4 = *reinterpret_cast<const float4*>(&sqm[0][jb]);

    #pragma unroll 4
    for (int f = 0; f < NUM_FREQS; f++) {
        // ---- issue phase: LDS + VMEM for f+1 into shadow registers ----
        float4 r01n = *reinterpret_cast<const float4*>(&sri[f + 1][jb]);
        float4 r23n = *reinterpret_cast<const float4*>(&sri[f + 1][jb + 2]);
        float4 qm4n = *reinterpret_cast<const float4*>(&sqm[f + 1][jb]);
        pA += NUM_BINS; pM += NUM_BINS;
        float4 P0n = pA[0];                  // f=63: lands in probeM/margin, unused
        float4 P1n = pA[64];
        float  w0n = pM[0];
        float  w1n = pM[64];
        __builtin_amdgcn_sched_barrier(0);   // keep issue phase above compute

        // ---- compute phase (uses current registers) ----
        const float qrv[4] = { r01.x, r01.z, r23.x, r23.z };
        const float qiv[4] = { r01.y, r01.w, r23.y, r23.w };
        const float qmv[4] = { qm4.x, qm4.y, qm4.z, qm4.w };

        #pragma unroll
        for (int p = 0; p < 4; p++) {
            float qr = qrv[p], qi = qiv[p], qm = qmv[p];
            {   // bin = lane
                float a = fmaf(qm, qm, P0.z);
                a = fmaf(P0.x, qr, a);
                a = fmaf(P0.y, qi, a);
                float d = __builtin_amdgcn_sqrtf(a);
                acc0[p] = fmaf(d, P0.w, fmaf(qm, w0, acc0[p]));
            }
            {   // bin = lane + 64
                float a = fmaf(qm, qm, P1.z);
                a = fmaf(P1.x, qr, a);
                a = fmaf(P1.y, qi, a);
                float d = __builtin_amdgcn_sqrtf(a);
                acc1[p] = fmaf(d, P1.w, fmaf(qm, w1, acc1[p]));
            }
        }

        // ---- rotate shadows -> live ----
        r01 = r01n; r23 = r23n; qm4 = qm4n;
        P0 = P0n; P1 = P1n; w0 = w0n; w1 = w1n;
    }

    #pragma unroll
    for (int p = 0; p < 4; p++) {
        size_t row = (size_t)(qbase + jb + p) * NUM_BINS;
        out[row + lane]      = acc0[p] + b0;     // coalesced
        out[row + 64 + lane] = acc1[p] + b1;     // coalesced
    }
}

// ---------------------------------------------------------------------------
// Fallback (only if ws_size is too small): fully self-contained, slower.
// ---------------------------------------------------------------------------
__global__ void fallback_kernel(const float* __restrict__ Q,
                                const float* __restrict__ rp,
                                const float* __restrict__ wraw,
                                const float* __restrict__ mw,
                                const float* __restrict__ bias,
                                float* __restrict__ out) {
    __shared__ float qn[HEAD_DIM];
    __shared__ float qmag[NUM_FREQS];
    __shared__ float red[NUM_BINS];
    const int t = threadIdx.x;
    const int q = blockIdx.x;

    float v = Q[(size_t)q * HEAD_DIM + t];
    red[t] = v * v;
    __syncthreads();
    for (int s = 64; s > 0; s >>= 1) {
        if (t < s) red[t] += red[t + s];
        __syncthreads();
    }
    float inv = 1.0f / (__builtin_amdgcn_sqrtf(red[0]) + EPS);
    qn[t] = v * inv;
    __syncthreads();
    if (t < NUM_FREQS) {
        float a = qn[t], c = qn[t + NUM_FREQS];
        qmag[t] = __builtin_amdgcn_sqrtf(fmaf(a, a, fmaf(c, c, EPS)));
    }
    __syncthreads();

    const int b = t;
    float acc = 0.0f;
    for (int f = 0; f < NUM_FREQS; f++) {
        float pr = rp[(size_t)b * HEAD_DIM + f];
        float pi = rp[(size_t)b * HEAD_DIM + NUM_FREQS + f];
        float w  = wraw[(size_t)b * NUM_FREQS + f];
        float ew = -(fmaxf(w, 0.0f) + log1pf(expf(-fabsf(w))));
        float er = pr - qn[f];
        float ei = pi - qn[f + NUM_FREQS];
        float d  = __builtin_amdgcn_sqrtf(fmaf(er, er, fmaf(ei, ei, EPS)));
        acc = fmaf(d, ew, fmaf(qmag[f], mw[(size_t)b * NUM_FREQS + f], acc));
    }
    out[(size_t)q * NUM_BINS + b] = acc + bias[b];
}

// ---------------------------------------------------------------------------
extern "C" void kernel_launch(void* const* d_in, const int* in_sizes, int n_in,
                              void* d_out, int out_size, void* d_ws, size_t ws_size,
                              hipStream_t stream) {
    const float* Q    = (const float*)d_in[0];
    const float* rp   = (const float*)d_in[1];
    const float* wraw = (const float*)d_in[2];
    const float* mw   = (const float*)d_in[3];
    const float* bias = (const float*)d_in[4];
    float* out = (float*)d_out;

    const size_t pABytes = (size_t)NUM_FREQS * NUM_BINS * sizeof(float4);  // 128 KiB
    const size_t pMBytes = (size_t)NUM_FREQS * NUM_BINS * sizeof(float);   //  32 KiB
    const size_t need    = pABytes + pMBytes + 4096;   // + margin for f=63 prefetch

    if (ws_size >= need) {
        float4* probeA = (float4*)d_ws;
        float*  probeM = (float*)((char*)d_ws + pABytes);

        hipLaunchKernelGGL(prep_probe, dim3(32), dim3(256), 0, stream,
                           rp, wraw, mw, probeA, probeM);
        hipLaunchKernelGGL(main_kernel, dim3(NUM_QUERIES / NQB), dim3(256), 0,
                           stream, probeA, probeM, Q, bias, out);
    } else {
        hipLaunchKernelGGL(fallback_kernel, dim3(NUM_QUERIES), dim3(NUM_BINS), 0,
                           stream, Q, rp, wraw, mw, bias, out);
    }
}